// Round 13
// baseline (210.667 us; speedup 1.0000x reference)
//
#include <hip/hip_runtime.h>

// WaveletFeatureExtractor: db4 wavedec (5 levels, symmetric pad) -> adaptive pool 128
// -> per-level 128x128 MLP (ReLU) -> fused 640->512 MLP (ReLU).
//
// Round 13: algebraic restructure. x -> pooled is LINEAR and each pooled output
// depends on a contiguous x-window (<=381 samples). So:
//  build_w: per output c, compute matrix row exactly via the ADJOINT cascade
//    (scatter g_in[symfold(2j-6+t)] += f[t]*g_out[j]; fixed-t targets are
//    distinct by parity -> j-parallel race-free, t barrier-serialized).
//    Stores f16 rows [640][384] + (sx,nk) meta in d_ws. Runs every launch.
//  banded_kernel: one block per row; x row staged in LDS (64KB, 2 blocks/CU);
//    thread c = one dot over its window; per-lane phase=tid&7 granule rotation
//    spreads the 32-granule bucket stride to the structural-minimum 8 phases.
//  Fallback to the r10 cascade kernel if ws_size too small. mlp = r8.

#define BATCH   2048
#define SIGLEN  16384
#define N1      8195
#define N2      4101
#define N3      2054
#define N4      1030
#define N5      518
#define POOLP   128
#define COMB    640
#define OUTD    512
#define WLEN    384   // padded weight-row length (max true window 381)

typedef __fp16 h2 __attribute__((ext_vector_type(2)));

__device__ constexpr float LO[8] = {
     0.2303778133088965f,   0.7148465705529157f,   0.6308807679298589f,
    -0.027983769416859854f, -0.18703481171909309f,  0.030841381835560764f,
     0.0328830116668852f,  -0.010597401785069032f };
__device__ constexpr float HI[8] = {
    -0.010597401785069032f, -0.0328830116668852f,   0.030841381835560764f,
     0.18703481171909309f,  -0.027983769416859854f, -0.6308807679298589f,
     0.7148465705529157f,  -0.2303778133088965f };

// ---------------- build_w: adjoint cascade -> banded rows ----------------
// Forward identity (matches the verified cascade): out[j] = sum_t f[t] * in[symfold(2j-6+t, Nin)]
// slot chains: 0:cA5 = LO^5; 1:cD5 = HI,LO^4; 2:cD4 = HI,LO^3; 3:cD3 = HI,LO^2; 4:cD2 = HI,LO.
__global__ __launch_bounds__(128) void build_w(h2* __restrict__ wt,     // [640][WLEN/2]
                                               int2* __restrict__ meta) // [640] (sx, nk)
{
    __shared__ float g0[512], g1[512];
    const int c = blockIdx.x;
    const int slot = c >> 7, p = c & 127;
    const int tid = threadIdx.x;

    const int bandN[5] = {N5, N5, N4, N3, N2};
    const int M = bandN[slot];
    const int s = (p * M) >> 7;
    const int e = ((p + 1) * M + 127) >> 7;

    for (int i = tid; i < 512; i += 128) { g0[i] = 0.f; g1[i] = 0.f; }
    __syncthreads();
    const float inv = 1.f / (float)(e - s);
    for (int i = tid; i < e - s; i += 128) g0[i] = inv;
    __syncthreads();

    float* cur = g0;
    float* nxt = g1;
    int ws = s, we = e;

    const int nsteps = (slot <= 1) ? 5 : (6 - slot);     // 5,5,4,3,2
    const int nins[5] = {N4, N3, N2, N1, SIGLEN};
    const int start = 5 - nsteps;

    for (int st = 0; st < nsteps; ++st) {
        const int Nin = nins[start + st];
        const bool useHI = (st == 0 && slot >= 1);
        const int nws = (2 * ws - 6 < 0) ? 0 : (2 * ws - 6);
        const int nwe = (2 * we < Nin) ? (2 * we) : Nin;
        for (int i = tid; i < nwe - nws; i += 128) nxt[i] = 0.f;
        __syncthreads();
        for (int t = 0; t < 8; ++t) {
            const float f = useHI ? HI[t] : LO[t];
            for (int j = ws + tid; j < we; j += 128) {
                int idx = 2 * j - 6 + t;
                idx = (idx < 0) ? (-1 - idx) : idx;
                idx = (idx >= Nin) ? (2 * Nin - 1 - idx) : idx;
                nxt[idx - nws] += f * cur[j - ws];
            }
            __syncthreads();
        }
        float* tmp = cur; cur = nxt; nxt = tmp;
        ws = nws; we = nwe;
    }

    const int sx0 = ws & ~3;
    int len = we - sx0;
    if (len > WLEN) len = WLEN;
    const int nk = (len + 3) >> 2;
    if (tid == 0) meta[c] = make_int2(sx0, nk);
    __fp16* wrow = reinterpret_cast<__fp16*>(wt + (size_t)c * (WLEN / 2));
    for (int i = tid; i < WLEN; i += 128) {
        const int idx = sx0 + i;
        const float v = (i < len && idx >= ws && idx < we) ? cur[idx - ws] : 0.f;
        wrow[i] = (__fp16)v;
    }
}

// ---------------- banded dot kernel: pooled[row][c] = dot(x window, W[c]) ----
__global__ __launch_bounds__(640) void banded_kernel(const float* __restrict__ x,
                                                     const h2* __restrict__ wt,
                                                     const int2* __restrict__ meta,
                                                     float* __restrict__ pooled) {
    __shared__ __align__(16) float xs[SIGLEN + 4];
    const int tid = threadIdx.x;
    const int row = blockIdx.x;
    const float* __restrict__ xr = x + (size_t)row * SIGLEN;

    for (int i = tid; i < SIGLEN / 4; i += 640) {
        *reinterpret_cast<float4*>(xs + 4 * i) = *reinterpret_cast<const float4*>(xr + 4 * i);
    }
    if (tid < 4) xs[SIGLEN + tid] = 0.f;
    __syncthreads();

    const int c = tid;
    const int2 m = meta[c];
    const int sx = m.x, nk = m.y;
    const h2* __restrict__ wrow = wt + (size_t)c * (WLEN / 2);
    const int phase = tid & 7;

    float acc = 0.f;
    for (int k = 0; k < nk; ++k) {
        int kk = k + phase; if (kk >= nk) kk -= nk;
        const float4 xv = *reinterpret_cast<const float4*>(xs + sx + 4 * kk);
        const float2 wraw = *reinterpret_cast<const float2*>(wrow + kk * 2);
        const h2 w01 = __builtin_bit_cast(h2, wraw.x);
        const h2 w23 = __builtin_bit_cast(h2, wraw.y);
        acc += xv.x * (float)w01.x + xv.y * (float)w01.y
             + xv.z * (float)w23.x + xv.w * (float)w23.y;
    }
    pooled[(size_t)row * COMB + c] = acc;
}

// ---------------- Fallback dwt cascade (round 10, proven 77us) ----------------

#define SWZ(i) ((i) ^ ((((i) >> 5) & 7) << 2))
#define NTHR 512

__device__ __forceinline__ int symfold(int idx, int n) {
    idx = (idx < 0) ? (-1 - idx) : idx;
    idx = (idx >= n) ? (2 * n - 1 - idx) : idx;
    return idx;
}
constexpr int cmin(int a, int b) { return a < b ? a : b; }
constexpr int cmax(int a, int b) { return a > b ? a : b; }

template<int SS, int SE, int BSRC, int NSRC, int S, int E, int BDST>
__device__ __forceinline__ void dwt_chunk(const float* __restrict__ src,
                                          float* __restrict__ dstA,
                                          float* __restrict__ dstD, int tid) {
    for (int j0 = (S & ~3) + tid * 4; j0 < E; j0 += NTHR * 4) {
        const int rb = 2 * j0 - 8;
        if ((rb >= SS) && (2 * j0 + 7 <= SE - 1) && (j0 + 4 <= E)) {
            const int lrb = rb - BSRC;
            const float4 v0 = *reinterpret_cast<const float4*>(src + SWZ(lrb));
            const float4 v1 = *reinterpret_cast<const float4*>(src + SWZ(lrb + 4));
            const float4 v2 = *reinterpret_cast<const float4*>(src + SWZ(lrb + 8));
            const float4 v3 = *reinterpret_cast<const float4*>(src + SWZ(lrb + 12));
            float w[16];
            w[0]=v0.x;  w[1]=v0.y;  w[2]=v0.z;  w[3]=v0.w;
            w[4]=v1.x;  w[5]=v1.y;  w[6]=v1.z;  w[7]=v1.w;
            w[8]=v2.x;  w[9]=v2.y;  w[10]=v2.z; w[11]=v2.w;
            w[12]=v3.x; w[13]=v3.y; w[14]=v3.z; w[15]=v3.w;
            float a[4], d[4];
#pragma unroll
            for (int k = 0; k < 4; ++k) {
                float aa = 0.f, dd = 0.f;
#pragma unroll
                for (int t = 0; t < 8; ++t) {
                    const float v = w[2 + 2 * k + t];
                    aa = fmaf(v, LO[t], aa);
                    dd = fmaf(v, HI[t], dd);
                }
                a[k] = aa; d[k] = dd;
            }
            const int ds = j0 - BDST;
            *reinterpret_cast<float4*>(dstA + SWZ(ds)) = make_float4(a[0], a[1], a[2], a[3]);
            *reinterpret_cast<float4*>(dstD + SWZ(ds)) = make_float4(d[0], d[1], d[2], d[3]);
        } else {
            for (int k = 0; k < 4; ++k) {
                const int j = j0 + k;
                if (j < S || j >= E) continue;
                float aa = 0.f, dd = 0.f;
#pragma unroll
                for (int t = 0; t < 8; ++t) {
                    const int idx = symfold(2 * j - 6 + t, NSRC);
                    const float v = src[SWZ(idx - BSRC)];
                    aa = fmaf(v, LO[t], aa);
                    dd = fmaf(v, HI[t], dd);
                }
                dstA[SWZ(j - BDST)] = aa;
                dstD[SWZ(j - BDST)] = dd;
            }
        }
    }
}

template<int S, int E, int BDST>
__device__ __forceinline__ void dwt_l1(const float* __restrict__ xr,
                                       float* __restrict__ dstA, int tid) {
    for (int j0 = (S & ~3) + tid * 4; j0 < E; j0 += NTHR * 4) {
        const int rb = 2 * j0 - 8;
        if ((rb >= 0) && (2 * j0 + 7 <= SIGLEN - 1) && (j0 + 4 <= E)) {
            const float4* s4 = reinterpret_cast<const float4*>(xr + rb);
            const float4 v0 = s4[0], v1 = s4[1], v2 = s4[2], v3 = s4[3];
            float w[16];
            w[0]=v0.x;  w[1]=v0.y;  w[2]=v0.z;  w[3]=v0.w;
            w[4]=v1.x;  w[5]=v1.y;  w[6]=v1.z;  w[7]=v1.w;
            w[8]=v2.x;  w[9]=v2.y;  w[10]=v2.z; w[11]=v2.w;
            w[12]=v3.x; w[13]=v3.y; w[14]=v3.z; w[15]=v3.w;
            float a[4];
#pragma unroll
            for (int k = 0; k < 4; ++k) {
                float aa = 0.f;
#pragma unroll
                for (int t = 0; t < 8; ++t) aa = fmaf(w[2 + 2 * k + t], LO[t], aa);
                a[k] = aa;
            }
            *reinterpret_cast<float4*>(dstA + SWZ(j0 - BDST)) = make_float4(a[0], a[1], a[2], a[3]);
        } else {
            for (int k = 0; k < 4; ++k) {
                const int j = j0 + k;
                if (j < S || j >= E) continue;
                float aa = 0.f;
#pragma unroll
                for (int t = 0; t < 8; ++t) {
                    const int idx = symfold(2 * j - 6 + t, SIGLEN);
                    aa = fmaf(xr[idx], LO[t], aa);
                }
                dstA[SWZ(j - BDST)] = aa;
            }
        }
    }
}

template<int N, int BASE, int P0>
__device__ __forceinline__ void pool64(const float* __restrict__ buf,
                                       float* __restrict__ dst, int tid) {
    const int p = P0 + (tid >> 3), sub = tid & 7;
    const int s = (p * N) >> 7;
    const int e = ((p + 1) * N + 127) >> 7;
    float acc = 0.f;
    for (int t = s + sub; t < e; t += 8) acc += buf[SWZ(t - BASE)];
    acc += __shfl_xor(acc, 1);
    acc += __shfl_xor(acc, 2);
    acc += __shfl_xor(acc, 4);
    if (sub == 0) dst[p] = acc / (float)(e - s);
}

template<int B>
__device__ __forceinline__ void dwt_body(const float* __restrict__ xr,
                                         float* __restrict__ pr,
                                         float* __restrict__ A, float* __restrict__ Bb,
                                         float* __restrict__ D1, float* __restrict__ D2,
                                         int tid) {
    constexpr int p0 = B * 64;
    constexpr int sP5 = (p0 * N5) >> 7, eP5 = ((p0 + 64) * N5 + 127) >> 7;
    constexpr int sP4 = (p0 * N4) >> 7, eP4 = ((p0 + 64) * N4 + 127) >> 7;
    constexpr int sP3 = (p0 * N3) >> 7, eP3 = ((p0 + 64) * N3 + 127) >> 7;
    constexpr int sP2 = (p0 * N2) >> 7, eP2 = ((p0 + 64) * N2 + 127) >> 7;
    constexpr int s5 = sP5, e5 = cmin(eP5, N5);
    constexpr int s4 = cmax(cmin(sP4, 2 * s5 - 6), 0);
    constexpr int e4 = cmin(cmax(eP4, 2 * e5), N4);
    constexpr int s3 = cmax(cmin(sP3, 2 * s4 - 6), 0);
    constexpr int e3 = cmin(cmax(eP3, 2 * e4), N3);
    constexpr int s2 = cmax(cmin(sP2, 2 * s3 - 6), 0);
    constexpr int e2 = cmin(cmax(eP2, 2 * e3), N2);
    constexpr int s1 = cmax(2 * s2 - 6, 0);
    constexpr int e1 = cmin(2 * e2, N1);
    constexpr int b1 = (s1 & ~3) - 8, b2 = (s2 & ~3) - 8, b3 = (s3 & ~3) - 8;
    constexpr int b4 = (s4 & ~3) - 8, b5 = (s5 & ~3) - 8;

    dwt_l1<s1, e1, b1>(xr, A, tid);
    __syncthreads();
    dwt_chunk<s1, e1, b1, N1, s2, e2, b2>(A, Bb, D1, tid);
    __syncthreads();
    dwt_chunk<s2, e2, b2, N2, s3, e3, b3>(Bb, A, D2, tid);
    pool64<N2, b2, p0>(D1, pr + 4 * POOLP, tid);
    __syncthreads();
    dwt_chunk<s3, e3, b3, N3, s4, e4, b4>(A, Bb, D1, tid);
    pool64<N3, b3, p0>(D2, pr + 3 * POOLP, tid);
    __syncthreads();
    dwt_chunk<s4, e4, b4, N4, s5, e5, b5>(Bb, A, D2, tid);
    pool64<N4, b4, p0>(D1, pr + 2 * POOLP, tid);
    __syncthreads();
    pool64<N5, b5, p0>(A,  pr + 0 * POOLP, tid);
    pool64<N5, b5, p0>(D2, pr + 1 * POOLP, tid);
}

__global__ __launch_bounds__(NTHR, 4) void dwt_pool_kernel(const float* __restrict__ x,
                                                           float* __restrict__ pooled) {
    __shared__ __align__(16) float A[4192];
    __shared__ __align__(16) float Bb[2144];
    __shared__ __align__(16) float D1[2144];
    __shared__ __align__(16) float D2[1088];
    const int tid = threadIdx.x;
    const int row = blockIdx.x >> 1;
    const float* __restrict__ xr = x + (size_t)row * SIGLEN;
    float* __restrict__ pr = pooled + (size_t)row * COMB;
    if (blockIdx.x & 1) dwt_body<1>(xr, pr, A, Bb, D1, D2, tid);
    else                dwt_body<0>(xr, pr, A, Bb, D1, D2, tid);
}

// ---------------- MLP (unchanged from round 8) ----------------

#define LW_PAIRS (5 * 128 * 128 / 2)
#define FW_PAIRS (512 * 640 / 2)

__global__ __launch_bounds__(256) void pack_w(const float* __restrict__ lw,
                                              const float* __restrict__ fw,
                                              h2* __restrict__ lwh,
                                              h2* __restrict__ fwh) {
    const int i = blockIdx.x * 256 + threadIdx.x;
    if (i < LW_PAIRS) {
        const float2 v = reinterpret_cast<const float2*>(lw)[i];
        lwh[i] = __builtin_amdgcn_cvt_pkrtz(v.x, v.y);
    } else if (i < LW_PAIRS + FW_PAIRS) {
        const float2 v = reinterpret_cast<const float2*>(fw)[i - LW_PAIRS];
        fwh[i - LW_PAIRS] = __builtin_amdgcn_cvt_pkrtz(v.x, v.y);
    }
}

__global__ __launch_bounds__(1024, 4) void mlp_kernel(const float* __restrict__ pooled,
                                                      const h2* __restrict__ lwh,
                                                      const float* __restrict__ lb,
                                                      const h2* __restrict__ fwh,
                                                      const float* __restrict__ fb,
                                                      float* __restrict__ out) {
    __shared__ h2 sph[8][COMB / 2];
    __shared__ h2 sch[8][COMB / 2];
    const int tid = threadIdx.x;
    const int r0 = blockIdx.x * 8;

    const float2* __restrict__ srcp = reinterpret_cast<const float2*>(pooled + (size_t)r0 * COMB);
    for (int i = tid; i < 8 * (COMB / 2); i += 1024) {
        const float2 v = srcp[i];
        (&sph[0][0])[i] = __builtin_amdgcn_cvt_pkrtz(v.x, v.y);
    }
    __syncthreads();

    for (int idx = tid; idx < COMB * 2; idx += 1024) {
        const int c = idx >> 1, rh = (idx & 1) * 4;
        const h2* __restrict__ w = lwh + (size_t)c * 64;
        const int lb2 = (c >> 7) * 64;
        const float bias = lb[c];
        float acc[4] = {bias, bias, bias, bias};
        for (int t2 = 0; t2 < 64; t2 += 4) {
            const float4 wraw = *reinterpret_cast<const float4*>(w + t2);
            const h2 w0 = __builtin_bit_cast(h2, wraw.x);
            const h2 w1 = __builtin_bit_cast(h2, wraw.y);
            const h2 w2 = __builtin_bit_cast(h2, wraw.z);
            const h2 w3 = __builtin_bit_cast(h2, wraw.w);
#pragma unroll
            for (int r = 0; r < 4; ++r) {
                const float4 praw = *reinterpret_cast<const float4*>(&sph[rh + r][lb2 + t2]);
                acc[r] = __builtin_amdgcn_fdot2(__builtin_bit_cast(h2, praw.x), w0, acc[r], false);
                acc[r] = __builtin_amdgcn_fdot2(__builtin_bit_cast(h2, praw.y), w1, acc[r], false);
                acc[r] = __builtin_amdgcn_fdot2(__builtin_bit_cast(h2, praw.z), w2, acc[r], false);
                acc[r] = __builtin_amdgcn_fdot2(__builtin_bit_cast(h2, praw.w), w3, acc[r], false);
            }
        }
        __fp16* __restrict__ schf = reinterpret_cast<__fp16*>(&sch[0][0]);
#pragma unroll
        for (int r = 0; r < 4; ++r) schf[(rh + r) * COMB + c] = (__fp16)fmaxf(acc[r], 0.f);
    }
    __syncthreads();

    {
        const int c = tid >> 1, rh = (tid & 1) * 4;
        const h2* __restrict__ w = fwh + (size_t)c * (COMB / 2);
        const float bias = fb[c];
        float acc[4] = {bias, bias, bias, bias};
        for (int t2 = 0; t2 < COMB / 2; t2 += 4) {
            const float4 wraw = *reinterpret_cast<const float4*>(w + t2);
            const h2 w0 = __builtin_bit_cast(h2, wraw.x);
            const h2 w1 = __builtin_bit_cast(h2, wraw.y);
            const h2 w2 = __builtin_bit_cast(h2, wraw.z);
            const h2 w3 = __builtin_bit_cast(h2, wraw.w);
#pragma unroll
            for (int r = 0; r < 4; ++r) {
                const float4 craw = *reinterpret_cast<const float4*>(&sch[rh + r][t2]);
                acc[r] = __builtin_amdgcn_fdot2(__builtin_bit_cast(h2, craw.x), w0, acc[r], false);
                acc[r] = __builtin_amdgcn_fdot2(__builtin_bit_cast(h2, craw.y), w1, acc[r], false);
                acc[r] = __builtin_amdgcn_fdot2(__builtin_bit_cast(h2, craw.z), w2, acc[r], false);
                acc[r] = __builtin_amdgcn_fdot2(__builtin_bit_cast(h2, craw.w), w3, acc[r], false);
            }
        }
#pragma unroll
        for (int r = 0; r < 4; ++r) {
            out[(size_t)(r0 + rh + r) * OUTD + c] = fmaxf(acc[r], 0.f);
        }
    }
}

__global__ __launch_bounds__(512) void mlp_kernel_fb(const float* __restrict__ pooled,
                                                     const float* __restrict__ lw,
                                                     const float* __restrict__ lb,
                                                     const float* __restrict__ fw,
                                                     const float* __restrict__ fb,
                                                     float* __restrict__ out) {
    __shared__ h2 sph[8][COMB / 2];
    __shared__ h2 sch[8][COMB / 2];
    const int tid = threadIdx.x;
    const int r0 = blockIdx.x * 8;
    const float2* __restrict__ srcp = reinterpret_cast<const float2*>(pooled + (size_t)r0 * COMB);
    for (int i = tid; i < 8 * (COMB / 2); i += 512) {
        const float2 v = srcp[i];
        (&sph[0][0])[i] = __builtin_amdgcn_cvt_pkrtz(v.x, v.y);
    }
    __syncthreads();
    for (int c = tid; c < COMB; c += 512) {
        const float* __restrict__ w = lw + (size_t)c * POOLP;
        const int lb2 = (c >> 7) * (POOLP / 2);
        const float bias = lb[c];
        float acc[8];
#pragma unroll
        for (int r = 0; r < 8; ++r) acc[r] = bias;
        for (int t2 = 0; t2 < POOLP / 2; t2 += 4) {
            const float4 wa = *reinterpret_cast<const float4*>(w + t2 * 2);
            const float4 wb = *reinterpret_cast<const float4*>(w + t2 * 2 + 4);
            const h2 w0 = __builtin_amdgcn_cvt_pkrtz(wa.x, wa.y);
            const h2 w1 = __builtin_amdgcn_cvt_pkrtz(wa.z, wa.w);
            const h2 w2 = __builtin_amdgcn_cvt_pkrtz(wb.x, wb.y);
            const h2 w3 = __builtin_amdgcn_cvt_pkrtz(wb.z, wb.w);
#pragma unroll
            for (int r = 0; r < 8; ++r) {
                const float4 raw = *reinterpret_cast<const float4*>(&sph[r][lb2 + t2]);
                acc[r] = __builtin_amdgcn_fdot2(__builtin_bit_cast(h2, raw.x), w0, acc[r], false);
                acc[r] = __builtin_amdgcn_fdot2(__builtin_bit_cast(h2, raw.y), w1, acc[r], false);
                acc[r] = __builtin_amdgcn_fdot2(__builtin_bit_cast(h2, raw.z), w2, acc[r], false);
                acc[r] = __builtin_amdgcn_fdot2(__builtin_bit_cast(h2, raw.w), w3, acc[r], false);
            }
        }
        __fp16* __restrict__ schf = reinterpret_cast<__fp16*>(&sch[0][0]);
#pragma unroll
        for (int r = 0; r < 8; ++r) schf[r * COMB + c] = (__fp16)fmaxf(acc[r], 0.f);
    }
    __syncthreads();
    {
        const int j = tid;
        const float* __restrict__ w = fw + (size_t)j * COMB;
        const float bias = fb[j];
        float acc[8];
#pragma unroll
        for (int r = 0; r < 8; ++r) acc[r] = bias;
        for (int t2 = 0; t2 < COMB / 2; t2 += 4) {
            const float4 wa = *reinterpret_cast<const float4*>(w + t2 * 2);
            const float4 wb = *reinterpret_cast<const float4*>(w + t2 * 2 + 4);
            const h2 w0 = __builtin_amdgcn_cvt_pkrtz(wa.x, wa.y);
            const h2 w1 = __builtin_amdgcn_cvt_pkrtz(wa.z, wa.w);
            const h2 w2 = __builtin_amdgcn_cvt_pkrtz(wb.x, wb.y);
            const h2 w3 = __builtin_amdgcn_cvt_pkrtz(wb.z, wb.w);
#pragma unroll
            for (int r = 0; r < 8; ++r) {
                const float4 raw = *reinterpret_cast<const float4*>(&sch[r][t2]);
                acc[r] = __builtin_amdgcn_fdot2(__builtin_bit_cast(h2, raw.x), w0, acc[r], false);
                acc[r] = __builtin_amdgcn_fdot2(__builtin_bit_cast(h2, raw.y), w1, acc[r], false);
                acc[r] = __builtin_amdgcn_fdot2(__builtin_bit_cast(h2, raw.z), w2, acc[r], false);
                acc[r] = __builtin_amdgcn_fdot2(__builtin_bit_cast(h2, raw.w), w3, acc[r], false);
            }
        }
#pragma unroll
        for (int r = 0; r < 8; ++r) {
            out[(size_t)(r0 + r) * OUTD + j] = fmaxf(acc[r], 0.f);
        }
    }
}

extern "C" void kernel_launch(void* const* d_in, const int* in_sizes, int n_in,
                              void* d_out, int out_size, void* d_ws, size_t ws_size,
                              hipStream_t stream) {
    const float* x  = (const float*)d_in[0];
    const float* lw = (const float*)d_in[1];
    const float* lb = (const float*)d_in[2];
    const float* fw = (const float*)d_in[3];
    const float* fb = (const float*)d_in[4];
    float* out = (float*)d_out;

    char* base = (char*)d_ws;
    const size_t POOLED_B = (size_t)BATCH * COMB * 4;            // 5,242,880
    const size_t LWH_B    = (size_t)LW_PAIRS * 4;                // 163,840
    const size_t FWH_B    = (size_t)FW_PAIRS * 4;                // 655,360
    const size_t META_B   = (size_t)COMB * 8;                    // 5,120
    const size_t WT_B     = (size_t)COMB * WLEN * 2;             // 491,520

    float* pooled = (float*)base;
    h2*   lwh  = (h2*)(base + POOLED_B);
    h2*   fwh  = (h2*)(base + POOLED_B + LWH_B);
    int2* meta = (int2*)(base + POOLED_B + LWH_B + FWH_B);
    h2*   wt   = (h2*)(base + POOLED_B + LWH_B + FWH_B + META_B);

    const size_t NEED_MLP    = POOLED_B + LWH_B + FWH_B;
    const size_t NEED_BANDED = NEED_MLP + META_B + WT_B;

    if (ws_size >= NEED_BANDED) {
        build_w<<<COMB, 128, 0, stream>>>(wt, meta);
        banded_kernel<<<BATCH, COMB, 0, stream>>>(x, wt, meta, pooled);
    } else {
        dwt_pool_kernel<<<BATCH * 2, NTHR, 0, stream>>>(x, pooled);
    }

    if (ws_size >= NEED_MLP) {
        pack_w<<<(LW_PAIRS + FW_PAIRS + 255) / 256, 256, 0, stream>>>(lw, fw, lwh, fwh);
        mlp_kernel<<<BATCH / 8, 1024, 0, stream>>>(pooled, lwh, lb, fwh, fb, out);
    } else {
        mlp_kernel_fb<<<BATCH / 8, 512, 0, stream>>>(pooled, lw, lb, fw, fb, out);
    }
}

// Round 14
// 102.901 us; speedup vs baseline: 2.0473x; 2.0473x over previous
//
#include <hip/hip_runtime.h>

// WaveletFeatureExtractor: db4 wavedec (5 levels, symmetric pad) -> adaptive pool 128
// -> per-level 128x128 MLP (ReLU) -> fused 640->512 MLP (ReLU).
//
// Round 14: banded formulation (r13) with the dot kernel fixed:
//  - 8-lane-cooperative outputs: c=tid>>3, sub=tid&7; each 8-lane group reads a
//    contiguous 128B granule strip (all 32 banks exactly once -> structural
//    minimum phases, no rotation). 3x shfl_xor reduce. (r13: 39.4M conflicts
//    from per-lane phase rotation + divergence.)
//  - x staged in LDS as packed f16 (32KB -> 4 blocks/CU x 512thr = 32 waves),
//    fdot2 (2 MAC/instr). W f16 rows (WLEN=400, sx 8-aligned), L2-resident.
//  build_w (adjoint cascade) verified correct in r13 (absmax == cascade's).
//  Fallback to the r10 cascade if ws too small. mlp = r8.

#define BATCH   2048
#define SIGLEN  16384
#define N1      8195
#define N2      4101
#define N3      2054
#define N4      1030
#define N5      518
#define POOLP   128
#define COMB    640
#define OUTD    512
#define WLEN    400   // padded weight-row length (max true window 388 after 8-align)

typedef __fp16 h2 __attribute__((ext_vector_type(2)));

__device__ constexpr float LO[8] = {
     0.2303778133088965f,   0.7148465705529157f,   0.6308807679298589f,
    -0.027983769416859854f, -0.18703481171909309f,  0.030841381835560764f,
     0.0328830116668852f,  -0.010597401785069032f };
__device__ constexpr float HI[8] = {
    -0.010597401785069032f, -0.0328830116668852f,   0.030841381835560764f,
     0.18703481171909309f,  -0.027983769416859854f, -0.6308807679298589f,
     0.7148465705529157f,  -0.2303778133088965f };

// ---------------- build_w: adjoint cascade -> banded rows (verified r13) ------
__global__ __launch_bounds__(128) void build_w(h2* __restrict__ wt,     // [640][WLEN/2]
                                               int2* __restrict__ meta) // [640] (sx, nk granules of 8)
{
    __shared__ float g0[512], g1[512];
    const int c = blockIdx.x;
    const int slot = c >> 7, p = c & 127;
    const int tid = threadIdx.x;

    const int bandN[5] = {N5, N5, N4, N3, N2};
    const int M = bandN[slot];
    const int s = (p * M) >> 7;
    const int e = ((p + 1) * M + 127) >> 7;

    for (int i = tid; i < 512; i += 128) { g0[i] = 0.f; g1[i] = 0.f; }
    __syncthreads();
    const float inv = 1.f / (float)(e - s);
    for (int i = tid; i < e - s; i += 128) g0[i] = inv;
    __syncthreads();

    float* cur = g0;
    float* nxt = g1;
    int ws = s, we = e;

    const int nsteps = (slot <= 1) ? 5 : (6 - slot);     // 5,5,4,3,2
    const int nins[5] = {N4, N3, N2, N1, SIGLEN};
    const int start = 5 - nsteps;

    for (int st = 0; st < nsteps; ++st) {
        const int Nin = nins[start + st];
        const bool useHI = (st == 0 && slot >= 1);
        const int nws = (2 * ws - 6 < 0) ? 0 : (2 * ws - 6);
        const int nwe = (2 * we < Nin) ? (2 * we) : Nin;
        for (int i = tid; i < nwe - nws; i += 128) nxt[i] = 0.f;
        __syncthreads();
        for (int t = 0; t < 8; ++t) {
            const float f = useHI ? HI[t] : LO[t];
            for (int j = ws + tid; j < we; j += 128) {
                int idx = 2 * j - 6 + t;
                idx = (idx < 0) ? (-1 - idx) : idx;
                idx = (idx >= Nin) ? (2 * Nin - 1 - idx) : idx;
                nxt[idx - nws] += f * cur[j - ws];
            }
            __syncthreads();
        }
        float* tmp = cur; cur = nxt; nxt = tmp;
        ws = nws; we = nwe;
    }

    const int sx0 = ws & ~7;                 // 8-elem aligned for f16 b128 reads
    const int len = we - sx0;                // <= 388
    const int nk = (len + 7) >> 3;           // 8-elem granules, <= 49
    if (tid == 0) meta[c] = make_int2(sx0, nk);
    __fp16* wrow = reinterpret_cast<__fp16*>(wt + (size_t)c * (WLEN / 2));
    for (int i = tid; i < WLEN; i += 128) {
        const int idx = sx0 + i;
        const float v = (idx >= ws && idx < we) ? cur[idx - ws] : 0.f;
        wrow[i] = (__fp16)v;
    }
}

// ---------- banded dot: pooled[row][c] = dot(x window, W[c]), 8-lane coop ----
__global__ __launch_bounds__(512) void banded_kernel(const float* __restrict__ x,
                                                     const h2* __restrict__ wt,
                                                     const int2* __restrict__ meta,
                                                     float* __restrict__ pooled) {
    __shared__ __align__(16) unsigned int xs_u[SIGLEN / 2 + 4];  // packed f16 pairs, 32KB+16B
    const int tid = threadIdx.x;
    const int row = blockIdx.x;
    const float* __restrict__ xr = x + (size_t)row * SIGLEN;

    // stage x -> f16 pairs
    for (int i = tid; i < SIGLEN / 4; i += 512) {
        const float4 v = *reinterpret_cast<const float4*>(xr + 4 * i);
        const h2 p0 = __builtin_amdgcn_cvt_pkrtz(v.x, v.y);
        const h2 p1 = __builtin_amdgcn_cvt_pkrtz(v.z, v.w);
        uint2 pk;
        pk.x = __builtin_bit_cast(unsigned int, p0);
        pk.y = __builtin_bit_cast(unsigned int, p1);
        *reinterpret_cast<uint2*>(xs_u + 2 * i) = pk;
    }
    if (tid < 4) xs_u[SIGLEN / 2 + tid] = 0u;
    __syncthreads();

    const float* __restrict__ xs_f = reinterpret_cast<const float*>(xs_u);
    const int sub = tid & 7;
    const int cb  = tid >> 3;                 // 64 outputs per pass

#pragma unroll
    for (int pass = 0; pass < 10; ++pass) {
        const int c = pass * 64 + cb;
        const int2 m = meta[c];
        const int sxh = m.x >> 1;             // uint/float index of window start (16B-aligned)
        const int nk = m.y;
        const h2* __restrict__ wrow = wt + (size_t)c * (WLEN / 2);
        float acc = 0.f;
        for (int g = sub; g < nk; g += 8) {
            // 8 f16 of x and of w per granule; group of 8 lanes = contiguous 128B
            const float4 xv = *reinterpret_cast<const float4*>(xs_f + sxh + 4 * g);
            const float4 wv = *reinterpret_cast<const float4*>(wrow + 4 * g);
            acc = __builtin_amdgcn_fdot2(__builtin_bit_cast(h2, xv.x), __builtin_bit_cast(h2, wv.x), acc, false);
            acc = __builtin_amdgcn_fdot2(__builtin_bit_cast(h2, xv.y), __builtin_bit_cast(h2, wv.y), acc, false);
            acc = __builtin_amdgcn_fdot2(__builtin_bit_cast(h2, xv.z), __builtin_bit_cast(h2, wv.z), acc, false);
            acc = __builtin_amdgcn_fdot2(__builtin_bit_cast(h2, xv.w), __builtin_bit_cast(h2, wv.w), acc, false);
        }
        acc += __shfl_xor(acc, 1);
        acc += __shfl_xor(acc, 2);
        acc += __shfl_xor(acc, 4);
        if (sub == 0) pooled[(size_t)row * COMB + c] = acc;
    }
}

// ---------------- Fallback dwt cascade (round 10, proven) ----------------

#define SWZ(i) ((i) ^ ((((i) >> 5) & 7) << 2))
#define NTHR 512

__device__ __forceinline__ int symfold(int idx, int n) {
    idx = (idx < 0) ? (-1 - idx) : idx;
    idx = (idx >= n) ? (2 * n - 1 - idx) : idx;
    return idx;
}
constexpr int cmin(int a, int b) { return a < b ? a : b; }
constexpr int cmax(int a, int b) { return a > b ? a : b; }

template<int SS, int SE, int BSRC, int NSRC, int S, int E, int BDST>
__device__ __forceinline__ void dwt_chunk(const float* __restrict__ src,
                                          float* __restrict__ dstA,
                                          float* __restrict__ dstD, int tid) {
    for (int j0 = (S & ~3) + tid * 4; j0 < E; j0 += NTHR * 4) {
        const int rb = 2 * j0 - 8;
        if ((rb >= SS) && (2 * j0 + 7 <= SE - 1) && (j0 + 4 <= E)) {
            const int lrb = rb - BSRC;
            const float4 v0 = *reinterpret_cast<const float4*>(src + SWZ(lrb));
            const float4 v1 = *reinterpret_cast<const float4*>(src + SWZ(lrb + 4));
            const float4 v2 = *reinterpret_cast<const float4*>(src + SWZ(lrb + 8));
            const float4 v3 = *reinterpret_cast<const float4*>(src + SWZ(lrb + 12));
            float w[16];
            w[0]=v0.x;  w[1]=v0.y;  w[2]=v0.z;  w[3]=v0.w;
            w[4]=v1.x;  w[5]=v1.y;  w[6]=v1.z;  w[7]=v1.w;
            w[8]=v2.x;  w[9]=v2.y;  w[10]=v2.z; w[11]=v2.w;
            w[12]=v3.x; w[13]=v3.y; w[14]=v3.z; w[15]=v3.w;
            float a[4], d[4];
#pragma unroll
            for (int k = 0; k < 4; ++k) {
                float aa = 0.f, dd = 0.f;
#pragma unroll
                for (int t = 0; t < 8; ++t) {
                    const float v = w[2 + 2 * k + t];
                    aa = fmaf(v, LO[t], aa);
                    dd = fmaf(v, HI[t], dd);
                }
                a[k] = aa; d[k] = dd;
            }
            const int ds = j0 - BDST;
            *reinterpret_cast<float4*>(dstA + SWZ(ds)) = make_float4(a[0], a[1], a[2], a[3]);
            *reinterpret_cast<float4*>(dstD + SWZ(ds)) = make_float4(d[0], d[1], d[2], d[3]);
        } else {
            for (int k = 0; k < 4; ++k) {
                const int j = j0 + k;
                if (j < S || j >= E) continue;
                float aa = 0.f, dd = 0.f;
#pragma unroll
                for (int t = 0; t < 8; ++t) {
                    const int idx = symfold(2 * j - 6 + t, NSRC);
                    const float v = src[SWZ(idx - BSRC)];
                    aa = fmaf(v, LO[t], aa);
                    dd = fmaf(v, HI[t], dd);
                }
                dstA[SWZ(j - BDST)] = aa;
                dstD[SWZ(j - BDST)] = dd;
            }
        }
    }
}

template<int S, int E, int BDST>
__device__ __forceinline__ void dwt_l1(const float* __restrict__ xr,
                                       float* __restrict__ dstA, int tid) {
    for (int j0 = (S & ~3) + tid * 4; j0 < E; j0 += NTHR * 4) {
        const int rb = 2 * j0 - 8;
        if ((rb >= 0) && (2 * j0 + 7 <= SIGLEN - 1) && (j0 + 4 <= E)) {
            const float4* s4 = reinterpret_cast<const float4*>(xr + rb);
            const float4 v0 = s4[0], v1 = s4[1], v2 = s4[2], v3 = s4[3];
            float w[16];
            w[0]=v0.x;  w[1]=v0.y;  w[2]=v0.z;  w[3]=v0.w;
            w[4]=v1.x;  w[5]=v1.y;  w[6]=v1.z;  w[7]=v1.w;
            w[8]=v2.x;  w[9]=v2.y;  w[10]=v2.z; w[11]=v2.w;
            w[12]=v3.x; w[13]=v3.y; w[14]=v3.z; w[15]=v3.w;
            float a[4];
#pragma unroll
            for (int k = 0; k < 4; ++k) {
                float aa = 0.f;
#pragma unroll
                for (int t = 0; t < 8; ++t) aa = fmaf(w[2 + 2 * k + t], LO[t], aa);
                a[k] = aa;
            }
            *reinterpret_cast<float4*>(dstA + SWZ(j0 - BDST)) = make_float4(a[0], a[1], a[2], a[3]);
        } else {
            for (int k = 0; k < 4; ++k) {
                const int j = j0 + k;
                if (j < S || j >= E) continue;
                float aa = 0.f;
#pragma unroll
                for (int t = 0; t < 8; ++t) {
                    const int idx = symfold(2 * j - 6 + t, SIGLEN);
                    aa = fmaf(xr[idx], LO[t], aa);
                }
                dstA[SWZ(j - BDST)] = aa;
            }
        }
    }
}

template<int N, int BASE, int P0>
__device__ __forceinline__ void pool64(const float* __restrict__ buf,
                                       float* __restrict__ dst, int tid) {
    const int p = P0 + (tid >> 3), sub = tid & 7;
    const int s = (p * N) >> 7;
    const int e = ((p + 1) * N + 127) >> 7;
    float acc = 0.f;
    for (int t = s + sub; t < e; t += 8) acc += buf[SWZ(t - BASE)];
    acc += __shfl_xor(acc, 1);
    acc += __shfl_xor(acc, 2);
    acc += __shfl_xor(acc, 4);
    if (sub == 0) dst[p] = acc / (float)(e - s);
}

template<int B>
__device__ __forceinline__ void dwt_body(const float* __restrict__ xr,
                                         float* __restrict__ pr,
                                         float* __restrict__ A, float* __restrict__ Bb,
                                         float* __restrict__ D1, float* __restrict__ D2,
                                         int tid) {
    constexpr int p0 = B * 64;
    constexpr int sP5 = (p0 * N5) >> 7, eP5 = ((p0 + 64) * N5 + 127) >> 7;
    constexpr int sP4 = (p0 * N4) >> 7, eP4 = ((p0 + 64) * N4 + 127) >> 7;
    constexpr int sP3 = (p0 * N3) >> 7, eP3 = ((p0 + 64) * N3 + 127) >> 7;
    constexpr int sP2 = (p0 * N2) >> 7, eP2 = ((p0 + 64) * N2 + 127) >> 7;
    constexpr int s5 = sP5, e5 = cmin(eP5, N5);
    constexpr int s4 = cmax(cmin(sP4, 2 * s5 - 6), 0);
    constexpr int e4 = cmin(cmax(eP4, 2 * e5), N4);
    constexpr int s3 = cmax(cmin(sP3, 2 * s4 - 6), 0);
    constexpr int e3 = cmin(cmax(eP3, 2 * e4), N3);
    constexpr int s2 = cmax(cmin(sP2, 2 * s3 - 6), 0);
    constexpr int e2 = cmin(cmax(eP2, 2 * e3), N2);
    constexpr int s1 = cmax(2 * s2 - 6, 0);
    constexpr int e1 = cmin(2 * e2, N1);
    constexpr int b1 = (s1 & ~3) - 8, b2 = (s2 & ~3) - 8, b3 = (s3 & ~3) - 8;
    constexpr int b4 = (s4 & ~3) - 8, b5 = (s5 & ~3) - 8;

    dwt_l1<s1, e1, b1>(xr, A, tid);
    __syncthreads();
    dwt_chunk<s1, e1, b1, N1, s2, e2, b2>(A, Bb, D1, tid);
    __syncthreads();
    dwt_chunk<s2, e2, b2, N2, s3, e3, b3>(Bb, A, D2, tid);
    pool64<N2, b2, p0>(D1, pr + 4 * POOLP, tid);
    __syncthreads();
    dwt_chunk<s3, e3, b3, N3, s4, e4, b4>(A, Bb, D1, tid);
    pool64<N3, b3, p0>(D2, pr + 3 * POOLP, tid);
    __syncthreads();
    dwt_chunk<s4, e4, b4, N4, s5, e5, b5>(Bb, A, D2, tid);
    pool64<N4, b4, p0>(D1, pr + 2 * POOLP, tid);
    __syncthreads();
    pool64<N5, b5, p0>(A,  pr + 0 * POOLP, tid);
    pool64<N5, b5, p0>(D2, pr + 1 * POOLP, tid);
}

__global__ __launch_bounds__(NTHR, 4) void dwt_pool_kernel(const float* __restrict__ x,
                                                           float* __restrict__ pooled) {
    __shared__ __align__(16) float A[4192];
    __shared__ __align__(16) float Bb[2144];
    __shared__ __align__(16) float D1[2144];
    __shared__ __align__(16) float D2[1088];
    const int tid = threadIdx.x;
    const int row = blockIdx.x >> 1;
    const float* __restrict__ xr = x + (size_t)row * SIGLEN;
    float* __restrict__ pr = pooled + (size_t)row * COMB;
    if (blockIdx.x & 1) dwt_body<1>(xr, pr, A, Bb, D1, D2, tid);
    else                dwt_body<0>(xr, pr, A, Bb, D1, D2, tid);
}

// ---------------- MLP (unchanged from round 8) ----------------

#define LW_PAIRS (5 * 128 * 128 / 2)
#define FW_PAIRS (512 * 640 / 2)

__global__ __launch_bounds__(256) void pack_w(const float* __restrict__ lw,
                                              const float* __restrict__ fw,
                                              h2* __restrict__ lwh,
                                              h2* __restrict__ fwh) {
    const int i = blockIdx.x * 256 + threadIdx.x;
    if (i < LW_PAIRS) {
        const float2 v = reinterpret_cast<const float2*>(lw)[i];
        lwh[i] = __builtin_amdgcn_cvt_pkrtz(v.x, v.y);
    } else if (i < LW_PAIRS + FW_PAIRS) {
        const float2 v = reinterpret_cast<const float2*>(fw)[i - LW_PAIRS];
        fwh[i - LW_PAIRS] = __builtin_amdgcn_cvt_pkrtz(v.x, v.y);
    }
}

__global__ __launch_bounds__(1024, 4) void mlp_kernel(const float* __restrict__ pooled,
                                                      const h2* __restrict__ lwh,
                                                      const float* __restrict__ lb,
                                                      const h2* __restrict__ fwh,
                                                      const float* __restrict__ fb,
                                                      float* __restrict__ out) {
    __shared__ h2 sph[8][COMB / 2];
    __shared__ h2 sch[8][COMB / 2];
    const int tid = threadIdx.x;
    const int r0 = blockIdx.x * 8;

    const float2* __restrict__ srcp = reinterpret_cast<const float2*>(pooled + (size_t)r0 * COMB);
    for (int i = tid; i < 8 * (COMB / 2); i += 1024) {
        const float2 v = srcp[i];
        (&sph[0][0])[i] = __builtin_amdgcn_cvt_pkrtz(v.x, v.y);
    }
    __syncthreads();

    for (int idx = tid; idx < COMB * 2; idx += 1024) {
        const int c = idx >> 1, rh = (idx & 1) * 4;
        const h2* __restrict__ w = lwh + (size_t)c * 64;
        const int lb2 = (c >> 7) * 64;
        const float bias = lb[c];
        float acc[4] = {bias, bias, bias, bias};
        for (int t2 = 0; t2 < 64; t2 += 4) {
            const float4 wraw = *reinterpret_cast<const float4*>(w + t2);
            const h2 w0 = __builtin_bit_cast(h2, wraw.x);
            const h2 w1 = __builtin_bit_cast(h2, wraw.y);
            const h2 w2 = __builtin_bit_cast(h2, wraw.z);
            const h2 w3 = __builtin_bit_cast(h2, wraw.w);
#pragma unroll
            for (int r = 0; r < 4; ++r) {
                const float4 praw = *reinterpret_cast<const float4*>(&sph[rh + r][lb2 + t2]);
                acc[r] = __builtin_amdgcn_fdot2(__builtin_bit_cast(h2, praw.x), w0, acc[r], false);
                acc[r] = __builtin_amdgcn_fdot2(__builtin_bit_cast(h2, praw.y), w1, acc[r], false);
                acc[r] = __builtin_amdgcn_fdot2(__builtin_bit_cast(h2, praw.z), w2, acc[r], false);
                acc[r] = __builtin_amdgcn_fdot2(__builtin_bit_cast(h2, praw.w), w3, acc[r], false);
            }
        }
        __fp16* __restrict__ schf = reinterpret_cast<__fp16*>(&sch[0][0]);
#pragma unroll
        for (int r = 0; r < 4; ++r) schf[(rh + r) * COMB + c] = (__fp16)fmaxf(acc[r], 0.f);
    }
    __syncthreads();

    {
        const int c = tid >> 1, rh = (tid & 1) * 4;
        const h2* __restrict__ w = fwh + (size_t)c * (COMB / 2);
        const float bias = fb[c];
        float acc[4] = {bias, bias, bias, bias};
        for (int t2 = 0; t2 < COMB / 2; t2 += 4) {
            const float4 wraw = *reinterpret_cast<const float4*>(w + t2);
            const h2 w0 = __builtin_bit_cast(h2, wraw.x);
            const h2 w1 = __builtin_bit_cast(h2, wraw.y);
            const h2 w2 = __builtin_bit_cast(h2, wraw.z);
            const h2 w3 = __builtin_bit_cast(h2, wraw.w);
#pragma unroll
            for (int r = 0; r < 4; ++r) {
                const float4 craw = *reinterpret_cast<const float4*>(&sch[rh + r][t2]);
                acc[r] = __builtin_amdgcn_fdot2(__builtin_bit_cast(h2, craw.x), w0, acc[r], false);
                acc[r] = __builtin_amdgcn_fdot2(__builtin_bit_cast(h2, craw.y), w1, acc[r], false);
                acc[r] = __builtin_amdgcn_fdot2(__builtin_bit_cast(h2, craw.z), w2, acc[r], false);
                acc[r] = __builtin_amdgcn_fdot2(__builtin_bit_cast(h2, craw.w), w3, acc[r], false);
            }
        }
#pragma unroll
        for (int r = 0; r < 4; ++r) {
            out[(size_t)(r0 + rh + r) * OUTD + c] = fmaxf(acc[r], 0.f);
        }
    }
}

__global__ __launch_bounds__(512) void mlp_kernel_fb(const float* __restrict__ pooled,
                                                     const float* __restrict__ lw,
                                                     const float* __restrict__ lb,
                                                     const float* __restrict__ fw,
                                                     const float* __restrict__ fb,
                                                     float* __restrict__ out) {
    __shared__ h2 sph[8][COMB / 2];
    __shared__ h2 sch[8][COMB / 2];
    const int tid = threadIdx.x;
    const int r0 = blockIdx.x * 8;
    const float2* __restrict__ srcp = reinterpret_cast<const float2*>(pooled + (size_t)r0 * COMB);
    for (int i = tid; i < 8 * (COMB / 2); i += 512) {
        const float2 v = srcp[i];
        (&sph[0][0])[i] = __builtin_amdgcn_cvt_pkrtz(v.x, v.y);
    }
    __syncthreads();
    for (int c = tid; c < COMB; c += 512) {
        const float* __restrict__ w = lw + (size_t)c * POOLP;
        const int lb2 = (c >> 7) * (POOLP / 2);
        const float bias = lb[c];
        float acc[8];
#pragma unroll
        for (int r = 0; r < 8; ++r) acc[r] = bias;
        for (int t2 = 0; t2 < POOLP / 2; t2 += 4) {
            const float4 wa = *reinterpret_cast<const float4*>(w + t2 * 2);
            const float4 wb = *reinterpret_cast<const float4*>(w + t2 * 2 + 4);
            const h2 w0 = __builtin_amdgcn_cvt_pkrtz(wa.x, wa.y);
            const h2 w1 = __builtin_amdgcn_cvt_pkrtz(wa.z, wa.w);
            const h2 w2 = __builtin_amdgcn_cvt_pkrtz(wb.x, wb.y);
            const h2 w3 = __builtin_amdgcn_cvt_pkrtz(wb.z, wb.w);
#pragma unroll
            for (int r = 0; r < 8; ++r) {
                const float4 raw = *reinterpret_cast<const float4*>(&sph[r][lb2 + t2]);
                acc[r] = __builtin_amdgcn_fdot2(__builtin_bit_cast(h2, raw.x), w0, acc[r], false);
                acc[r] = __builtin_amdgcn_fdot2(__builtin_bit_cast(h2, raw.y), w1, acc[r], false);
                acc[r] = __builtin_amdgcn_fdot2(__builtin_bit_cast(h2, raw.z), w2, acc[r], false);
                acc[r] = __builtin_amdgcn_fdot2(__builtin_bit_cast(h2, raw.w), w3, acc[r], false);
            }
        }
        __fp16* __restrict__ schf = reinterpret_cast<__fp16*>(&sch[0][0]);
#pragma unroll
        for (int r = 0; r < 8; ++r) schf[r * COMB + c] = (__fp16)fmaxf(acc[r], 0.f);
    }
    __syncthreads();
    {
        const int j = tid;
        const float* __restrict__ w = fw + (size_t)j * COMB;
        const float bias = fb[j];
        float acc[8];
#pragma unroll
        for (int r = 0; r < 8; ++r) acc[r] = bias;
        for (int t2 = 0; t2 < COMB / 2; t2 += 4) {
            const float4 wa = *reinterpret_cast<const float4*>(w + t2 * 2);
            const float4 wb = *reinterpret_cast<const float4*>(w + t2 * 2 + 4);
            const h2 w0 = __builtin_amdgcn_cvt_pkrtz(wa.x, wa.y);
            const h2 w1 = __builtin_amdgcn_cvt_pkrtz(wa.z, wa.w);
            const h2 w2 = __builtin_amdgcn_cvt_pkrtz(wb.x, wb.y);
            const h2 w3 = __builtin_amdgcn_cvt_pkrtz(wb.z, wb.w);
#pragma unroll
            for (int r = 0; r < 8; ++r) {
                const float4 raw = *reinterpret_cast<const float4*>(&sch[r][t2]);
                acc[r] = __builtin_amdgcn_fdot2(__builtin_bit_cast(h2, raw.x), w0, acc[r], false);
                acc[r] = __builtin_amdgcn_fdot2(__builtin_bit_cast(h2, raw.y), w1, acc[r], false);
                acc[r] = __builtin_amdgcn_fdot2(__builtin_bit_cast(h2, raw.z), w2, acc[r], false);
                acc[r] = __builtin_amdgcn_fdot2(__builtin_bit_cast(h2, raw.w), w3, acc[r], false);
            }
        }
#pragma unroll
        for (int r = 0; r < 8; ++r) {
            out[(size_t)(r0 + r) * OUTD + j] = fmaxf(acc[r], 0.f);
        }
    }
}

extern "C" void kernel_launch(void* const* d_in, const int* in_sizes, int n_in,
                              void* d_out, int out_size, void* d_ws, size_t ws_size,
                              hipStream_t stream) {
    const float* x  = (const float*)d_in[0];
    const float* lw = (const float*)d_in[1];
    const float* lb = (const float*)d_in[2];
    const float* fw = (const float*)d_in[3];
    const float* fb = (const float*)d_in[4];
    float* out = (float*)d_out;

    char* base = (char*)d_ws;
    const size_t POOLED_B = (size_t)BATCH * COMB * 4;            // 5,242,880
    const size_t LWH_B    = (size_t)LW_PAIRS * 4;                // 163,840
    const size_t FWH_B    = (size_t)FW_PAIRS * 4;                // 655,360
    const size_t META_B   = (size_t)COMB * 8;                    // 5,120
    const size_t WT_B     = (size_t)COMB * WLEN * 2;             // 512,000

    float* pooled = (float*)base;
    h2*   lwh  = (h2*)(base + POOLED_B);
    h2*   fwh  = (h2*)(base + POOLED_B + LWH_B);
    int2* meta = (int2*)(base + POOLED_B + LWH_B + FWH_B);
    h2*   wt   = (h2*)(base + POOLED_B + LWH_B + FWH_B + META_B);

    const size_t NEED_MLP    = POOLED_B + LWH_B + FWH_B;
    const size_t NEED_BANDED = NEED_MLP + META_B + WT_B;

    if (ws_size >= NEED_BANDED) {
        build_w<<<COMB, 128, 0, stream>>>(wt, meta);
        banded_kernel<<<BATCH, 512, 0, stream>>>(x, wt, meta, pooled);
    } else {
        dwt_pool_kernel<<<BATCH * 2, NTHR, 0, stream>>>(x, pooled);
    }

    if (ws_size >= NEED_MLP) {
        pack_w<<<(LW_PAIRS + FW_PAIRS + 255) / 256, 256, 0, stream>>>(lw, fw, lwh, fwh);
        mlp_kernel<<<BATCH / 8, 1024, 0, stream>>>(pooled, lwh, lb, fwh, fb, out);
    } else {
        mlp_kernel_fb<<<BATCH / 8, 512, 0, stream>>>(pooled, lw, lb, fw, fb, out);
    }
}

// Round 15
// 97.272 us; speedup vs baseline: 2.1658x; 1.0579x over previous
//
#include <hip/hip_runtime.h>

// WaveletFeatureExtractor: db4 wavedec (5 levels, symmetric pad) -> adaptive pool 128
// -> per-level 128x128 MLP (ReLU) -> fused 640->512 MLP (ReLU).
//
// Round 15 = round 14 with the banded dot loop made COMPILE-TIME UNIFORM:
// rows padded to WLEN=448 (56 granules) -> each of 8 coop lanes owns exactly 7
// granules, fully unrolled -> 7 independent L2 loads in flight (r14: VGPR=16,
// VALUBusy=16%, runtime nk -> one load at a time, pure latency bound).
// xs padded +64 uints (zero) so padded windows stay in-bounds; w pad is zero.
// build_w (adjoint cascade, verified r13), mlp (r8), r10-cascade fallback.

#define BATCH   2048
#define SIGLEN  16384
#define N1      8195
#define N2      4101
#define N3      2054
#define N4      1030
#define N5      518
#define POOLP   128
#define COMB    640
#define OUTD    512
#define WLEN    448   // 56 granules of 8 f16; true window <= 388
#define NGRAN   7     // granules per lane (56/8)

typedef __fp16 h2 __attribute__((ext_vector_type(2)));

__device__ constexpr float LO[8] = {
     0.2303778133088965f,   0.7148465705529157f,   0.6308807679298589f,
    -0.027983769416859854f, -0.18703481171909309f,  0.030841381835560764f,
     0.0328830116668852f,  -0.010597401785069032f };
__device__ constexpr float HI[8] = {
    -0.010597401785069032f, -0.0328830116668852f,   0.030841381835560764f,
     0.18703481171909309f,  -0.027983769416859854f, -0.6308807679298589f,
     0.7148465705529157f,  -0.2303778133088965f };

// ---------------- build_w: adjoint cascade -> banded rows (verified r13) ------
__global__ __launch_bounds__(128) void build_w(h2* __restrict__ wt,     // [640][WLEN/2]
                                               int* __restrict__ meta)  // [640] sx
{
    __shared__ float g0[512], g1[512];
    const int c = blockIdx.x;
    const int slot = c >> 7, p = c & 127;
    const int tid = threadIdx.x;

    const int bandN[5] = {N5, N5, N4, N3, N2};
    const int M = bandN[slot];
    const int s = (p * M) >> 7;
    const int e = ((p + 1) * M + 127) >> 7;

    for (int i = tid; i < 512; i += 128) { g0[i] = 0.f; g1[i] = 0.f; }
    __syncthreads();
    const float inv = 1.f / (float)(e - s);
    for (int i = tid; i < e - s; i += 128) g0[i] = inv;
    __syncthreads();

    float* cur = g0;
    float* nxt = g1;
    int ws = s, we = e;

    const int nsteps = (slot <= 1) ? 5 : (6 - slot);     // 5,5,4,3,2
    const int nins[5] = {N4, N3, N2, N1, SIGLEN};
    const int start = 5 - nsteps;

    for (int st = 0; st < nsteps; ++st) {
        const int Nin = nins[start + st];
        const bool useHI = (st == 0 && slot >= 1);
        const int nws = (2 * ws - 6 < 0) ? 0 : (2 * ws - 6);
        const int nwe = (2 * we < Nin) ? (2 * we) : Nin;
        for (int i = tid; i < nwe - nws; i += 128) nxt[i] = 0.f;
        __syncthreads();
        for (int t = 0; t < 8; ++t) {
            const float f = useHI ? HI[t] : LO[t];
            for (int j = ws + tid; j < we; j += 128) {
                int idx = 2 * j - 6 + t;
                idx = (idx < 0) ? (-1 - idx) : idx;
                idx = (idx >= Nin) ? (2 * Nin - 1 - idx) : idx;
                nxt[idx - nws] += f * cur[j - ws];
            }
            __syncthreads();
        }
        float* tmp = cur; cur = nxt; nxt = tmp;
        ws = nws; we = nwe;
    }

    const int sx0 = ws & ~7;                 // 8-elem aligned for f16 b128 reads
    if (tid == 0) meta[c] = sx0;
    __fp16* wrow = reinterpret_cast<__fp16*>(wt + (size_t)c * (WLEN / 2));
    for (int i = tid; i < WLEN; i += 128) {
        const int idx = sx0 + i;
        const float v = (idx >= ws && idx < we) ? cur[idx - ws] : 0.f;
        wrow[i] = (__fp16)v;
    }
}

// ---------- banded dot: pooled[row][c] = dot(x window, W[c]), 8-lane coop ----
// Fixed 7 granules/lane, fully unrolled -> 7 L2 + 7 LDS loads in flight.
__global__ __launch_bounds__(512) void banded_kernel(const float* __restrict__ x,
                                                     const h2* __restrict__ wt,
                                                     const int* __restrict__ meta,
                                                     float* __restrict__ pooled) {
    __shared__ __align__(16) unsigned int xs_u[SIGLEN / 2 + 64];  // f16 pairs + zero pad
    const int tid = threadIdx.x;
    const int row = blockIdx.x;
    const float* __restrict__ xr = x + (size_t)row * SIGLEN;

    for (int i = tid; i < SIGLEN / 4; i += 512) {
        const float4 v = *reinterpret_cast<const float4*>(xr + 4 * i);
        const h2 p0 = __builtin_amdgcn_cvt_pkrtz(v.x, v.y);
        const h2 p1 = __builtin_amdgcn_cvt_pkrtz(v.z, v.w);
        uint2 pk;
        pk.x = __builtin_bit_cast(unsigned int, p0);
        pk.y = __builtin_bit_cast(unsigned int, p1);
        *reinterpret_cast<uint2*>(xs_u + 2 * i) = pk;
    }
    if (tid < 64) xs_u[SIGLEN / 2 + tid] = 0u;
    __syncthreads();

    const float* __restrict__ xs_f = reinterpret_cast<const float*>(xs_u);
    const int sub = tid & 7;
    const int cb  = tid >> 3;                 // 64 outputs per pass

#pragma unroll
    for (int pass = 0; pass < 10; ++pass) {
        const int c = pass * 64 + cb;
        const int sxh = meta[c] >> 1;         // float-index of window start (16B-aligned)
        const h2* __restrict__ wrow = wt + (size_t)c * (WLEN / 2);

        float4 xv[NGRAN], wv[NGRAN];
#pragma unroll
        for (int i = 0; i < NGRAN; ++i) {
            const int g = sub + 8 * i;
            xv[i] = *reinterpret_cast<const float4*>(xs_f + sxh + 4 * g);
            wv[i] = *reinterpret_cast<const float4*>(wrow + 4 * g);
        }
        float acc = 0.f;
#pragma unroll
        for (int i = 0; i < NGRAN; ++i) {
            acc = __builtin_amdgcn_fdot2(__builtin_bit_cast(h2, xv[i].x), __builtin_bit_cast(h2, wv[i].x), acc, false);
            acc = __builtin_amdgcn_fdot2(__builtin_bit_cast(h2, xv[i].y), __builtin_bit_cast(h2, wv[i].y), acc, false);
            acc = __builtin_amdgcn_fdot2(__builtin_bit_cast(h2, xv[i].z), __builtin_bit_cast(h2, wv[i].z), acc, false);
            acc = __builtin_amdgcn_fdot2(__builtin_bit_cast(h2, xv[i].w), __builtin_bit_cast(h2, wv[i].w), acc, false);
        }
        acc += __shfl_xor(acc, 1);
        acc += __shfl_xor(acc, 2);
        acc += __shfl_xor(acc, 4);
        if (sub == 0) pooled[(size_t)row * COMB + c] = acc;
    }
}

// ---------------- Fallback dwt cascade (round 10, proven) ----------------

#define SWZ(i) ((i) ^ ((((i) >> 5) & 7) << 2))
#define NTHR 512

__device__ __forceinline__ int symfold(int idx, int n) {
    idx = (idx < 0) ? (-1 - idx) : idx;
    idx = (idx >= n) ? (2 * n - 1 - idx) : idx;
    return idx;
}
constexpr int cmin(int a, int b) { return a < b ? a : b; }
constexpr int cmax(int a, int b) { return a > b ? a : b; }

template<int SS, int SE, int BSRC, int NSRC, int S, int E, int BDST>
__device__ __forceinline__ void dwt_chunk(const float* __restrict__ src,
                                          float* __restrict__ dstA,
                                          float* __restrict__ dstD, int tid) {
    for (int j0 = (S & ~3) + tid * 4; j0 < E; j0 += NTHR * 4) {
        const int rb = 2 * j0 - 8;
        if ((rb >= SS) && (2 * j0 + 7 <= SE - 1) && (j0 + 4 <= E)) {
            const int lrb = rb - BSRC;
            const float4 v0 = *reinterpret_cast<const float4*>(src + SWZ(lrb));
            const float4 v1 = *reinterpret_cast<const float4*>(src + SWZ(lrb + 4));
            const float4 v2 = *reinterpret_cast<const float4*>(src + SWZ(lrb + 8));
            const float4 v3 = *reinterpret_cast<const float4*>(src + SWZ(lrb + 12));
            float w[16];
            w[0]=v0.x;  w[1]=v0.y;  w[2]=v0.z;  w[3]=v0.w;
            w[4]=v1.x;  w[5]=v1.y;  w[6]=v1.z;  w[7]=v1.w;
            w[8]=v2.x;  w[9]=v2.y;  w[10]=v2.z; w[11]=v2.w;
            w[12]=v3.x; w[13]=v3.y; w[14]=v3.z; w[15]=v3.w;
            float a[4], d[4];
#pragma unroll
            for (int k = 0; k < 4; ++k) {
                float aa = 0.f, dd = 0.f;
#pragma unroll
                for (int t = 0; t < 8; ++t) {
                    const float v = w[2 + 2 * k + t];
                    aa = fmaf(v, LO[t], aa);
                    dd = fmaf(v, HI[t], dd);
                }
                a[k] = aa; d[k] = dd;
            }
            const int ds = j0 - BDST;
            *reinterpret_cast<float4*>(dstA + SWZ(ds)) = make_float4(a[0], a[1], a[2], a[3]);
            *reinterpret_cast<float4*>(dstD + SWZ(ds)) = make_float4(d[0], d[1], d[2], d[3]);
        } else {
            for (int k = 0; k < 4; ++k) {
                const int j = j0 + k;
                if (j < S || j >= E) continue;
                float aa = 0.f, dd = 0.f;
#pragma unroll
                for (int t = 0; t < 8; ++t) {
                    const int idx = symfold(2 * j - 6 + t, NSRC);
                    const float v = src[SWZ(idx - BSRC)];
                    aa = fmaf(v, LO[t], aa);
                    dd = fmaf(v, HI[t], dd);
                }
                dstA[SWZ(j - BDST)] = aa;
                dstD[SWZ(j - BDST)] = dd;
            }
        }
    }
}

template<int S, int E, int BDST>
__device__ __forceinline__ void dwt_l1(const float* __restrict__ xr,
                                       float* __restrict__ dstA, int tid) {
    for (int j0 = (S & ~3) + tid * 4; j0 < E; j0 += NTHR * 4) {
        const int rb = 2 * j0 - 8;
        if ((rb >= 0) && (2 * j0 + 7 <= SIGLEN - 1) && (j0 + 4 <= E)) {
            const float4* s4 = reinterpret_cast<const float4*>(xr + rb);
            const float4 v0 = s4[0], v1 = s4[1], v2 = s4[2], v3 = s4[3];
            float w[16];
            w[0]=v0.x;  w[1]=v0.y;  w[2]=v0.z;  w[3]=v0.w;
            w[4]=v1.x;  w[5]=v1.y;  w[6]=v1.z;  w[7]=v1.w;
            w[8]=v2.x;  w[9]=v2.y;  w[10]=v2.z; w[11]=v2.w;
            w[12]=v3.x; w[13]=v3.y; w[14]=v3.z; w[15]=v3.w;
            float a[4];
#pragma unroll
            for (int k = 0; k < 4; ++k) {
                float aa = 0.f;
#pragma unroll
                for (int t = 0; t < 8; ++t) aa = fmaf(w[2 + 2 * k + t], LO[t], aa);
                a[k] = aa;
            }
            *reinterpret_cast<float4*>(dstA + SWZ(j0 - BDST)) = make_float4(a[0], a[1], a[2], a[3]);
        } else {
            for (int k = 0; k < 4; ++k) {
                const int j = j0 + k;
                if (j < S || j >= E) continue;
                float aa = 0.f;
#pragma unroll
                for (int t = 0; t < 8; ++t) {
                    const int idx = symfold(2 * j - 6 + t, SIGLEN);
                    aa = fmaf(xr[idx], LO[t], aa);
                }
                dstA[SWZ(j - BDST)] = aa;
            }
        }
    }
}

template<int N, int BASE, int P0>
__device__ __forceinline__ void pool64(const float* __restrict__ buf,
                                       float* __restrict__ dst, int tid) {
    const int p = P0 + (tid >> 3), sub = tid & 7;
    const int s = (p * N) >> 7;
    const int e = ((p + 1) * N + 127) >> 7;
    float acc = 0.f;
    for (int t = s + sub; t < e; t += 8) acc += buf[SWZ(t - BASE)];
    acc += __shfl_xor(acc, 1);
    acc += __shfl_xor(acc, 2);
    acc += __shfl_xor(acc, 4);
    if (sub == 0) dst[p] = acc / (float)(e - s);
}

template<int B>
__device__ __forceinline__ void dwt_body(const float* __restrict__ xr,
                                         float* __restrict__ pr,
                                         float* __restrict__ A, float* __restrict__ Bb,
                                         float* __restrict__ D1, float* __restrict__ D2,
                                         int tid) {
    constexpr int p0 = B * 64;
    constexpr int sP5 = (p0 * N5) >> 7, eP5 = ((p0 + 64) * N5 + 127) >> 7;
    constexpr int sP4 = (p0 * N4) >> 7, eP4 = ((p0 + 64) * N4 + 127) >> 7;
    constexpr int sP3 = (p0 * N3) >> 7, eP3 = ((p0 + 64) * N3 + 127) >> 7;
    constexpr int sP2 = (p0 * N2) >> 7, eP2 = ((p0 + 64) * N2 + 127) >> 7;
    constexpr int s5 = sP5, e5 = cmin(eP5, N5);
    constexpr int s4 = cmax(cmin(sP4, 2 * s5 - 6), 0);
    constexpr int e4 = cmin(cmax(eP4, 2 * e5), N4);
    constexpr int s3 = cmax(cmin(sP3, 2 * s4 - 6), 0);
    constexpr int e3 = cmin(cmax(eP3, 2 * e4), N3);
    constexpr int s2 = cmax(cmin(sP2, 2 * s3 - 6), 0);
    constexpr int e2 = cmin(cmax(eP2, 2 * e3), N2);
    constexpr int s1 = cmax(2 * s2 - 6, 0);
    constexpr int e1 = cmin(2 * e2, N1);
    constexpr int b1 = (s1 & ~3) - 8, b2 = (s2 & ~3) - 8, b3 = (s3 & ~3) - 8;
    constexpr int b4 = (s4 & ~3) - 8, b5 = (s5 & ~3) - 8;

    dwt_l1<s1, e1, b1>(xr, A, tid);
    __syncthreads();
    dwt_chunk<s1, e1, b1, N1, s2, e2, b2>(A, Bb, D1, tid);
    __syncthreads();
    dwt_chunk<s2, e2, b2, N2, s3, e3, b3>(Bb, A, D2, tid);
    pool64<N2, b2, p0>(D1, pr + 4 * POOLP, tid);
    __syncthreads();
    dwt_chunk<s3, e3, b3, N3, s4, e4, b4>(A, Bb, D1, tid);
    pool64<N3, b3, p0>(D2, pr + 3 * POOLP, tid);
    __syncthreads();
    dwt_chunk<s4, e4, b4, N4, s5, e5, b5>(Bb, A, D2, tid);
    pool64<N4, b4, p0>(D1, pr + 2 * POOLP, tid);
    __syncthreads();
    pool64<N5, b5, p0>(A,  pr + 0 * POOLP, tid);
    pool64<N5, b5, p0>(D2, pr + 1 * POOLP, tid);
}

__global__ __launch_bounds__(NTHR, 4) void dwt_pool_kernel(const float* __restrict__ x,
                                                           float* __restrict__ pooled) {
    __shared__ __align__(16) float A[4192];
    __shared__ __align__(16) float Bb[2144];
    __shared__ __align__(16) float D1[2144];
    __shared__ __align__(16) float D2[1088];
    const int tid = threadIdx.x;
    const int row = blockIdx.x >> 1;
    const float* __restrict__ xr = x + (size_t)row * SIGLEN;
    float* __restrict__ pr = pooled + (size_t)row * COMB;
    if (blockIdx.x & 1) dwt_body<1>(xr, pr, A, Bb, D1, D2, tid);
    else                dwt_body<0>(xr, pr, A, Bb, D1, D2, tid);
}

// ---------------- MLP (unchanged from round 8) ----------------

#define LW_PAIRS (5 * 128 * 128 / 2)
#define FW_PAIRS (512 * 640 / 2)

__global__ __launch_bounds__(256) void pack_w(const float* __restrict__ lw,
                                              const float* __restrict__ fw,
                                              h2* __restrict__ lwh,
                                              h2* __restrict__ fwh) {
    const int i = blockIdx.x * 256 + threadIdx.x;
    if (i < LW_PAIRS) {
        const float2 v = reinterpret_cast<const float2*>(lw)[i];
        lwh[i] = __builtin_amdgcn_cvt_pkrtz(v.x, v.y);
    } else if (i < LW_PAIRS + FW_PAIRS) {
        const float2 v = reinterpret_cast<const float2*>(fw)[i - LW_PAIRS];
        fwh[i - LW_PAIRS] = __builtin_amdgcn_cvt_pkrtz(v.x, v.y);
    }
}

__global__ __launch_bounds__(1024, 4) void mlp_kernel(const float* __restrict__ pooled,
                                                      const h2* __restrict__ lwh,
                                                      const float* __restrict__ lb,
                                                      const h2* __restrict__ fwh,
                                                      const float* __restrict__ fb,
                                                      float* __restrict__ out) {
    __shared__ h2 sph[8][COMB / 2];
    __shared__ h2 sch[8][COMB / 2];
    const int tid = threadIdx.x;
    const int r0 = blockIdx.x * 8;

    const float2* __restrict__ srcp = reinterpret_cast<const float2*>(pooled + (size_t)r0 * COMB);
    for (int i = tid; i < 8 * (COMB / 2); i += 1024) {
        const float2 v = srcp[i];
        (&sph[0][0])[i] = __builtin_amdgcn_cvt_pkrtz(v.x, v.y);
    }
    __syncthreads();

    for (int idx = tid; idx < COMB * 2; idx += 1024) {
        const int c = idx >> 1, rh = (idx & 1) * 4;
        const h2* __restrict__ w = lwh + (size_t)c * 64;
        const int lb2 = (c >> 7) * 64;
        const float bias = lb[c];
        float acc[4] = {bias, bias, bias, bias};
        for (int t2 = 0; t2 < 64; t2 += 4) {
            const float4 wraw = *reinterpret_cast<const float4*>(w + t2);
            const h2 w0 = __builtin_bit_cast(h2, wraw.x);
            const h2 w1 = __builtin_bit_cast(h2, wraw.y);
            const h2 w2 = __builtin_bit_cast(h2, wraw.z);
            const h2 w3 = __builtin_bit_cast(h2, wraw.w);
#pragma unroll
            for (int r = 0; r < 4; ++r) {
                const float4 praw = *reinterpret_cast<const float4*>(&sph[rh + r][lb2 + t2]);
                acc[r] = __builtin_amdgcn_fdot2(__builtin_bit_cast(h2, praw.x), w0, acc[r], false);
                acc[r] = __builtin_amdgcn_fdot2(__builtin_bit_cast(h2, praw.y), w1, acc[r], false);
                acc[r] = __builtin_amdgcn_fdot2(__builtin_bit_cast(h2, praw.z), w2, acc[r], false);
                acc[r] = __builtin_amdgcn_fdot2(__builtin_bit_cast(h2, praw.w), w3, acc[r], false);
            }
        }
        __fp16* __restrict__ schf = reinterpret_cast<__fp16*>(&sch[0][0]);
#pragma unroll
        for (int r = 0; r < 4; ++r) schf[(rh + r) * COMB + c] = (__fp16)fmaxf(acc[r], 0.f);
    }
    __syncthreads();

    {
        const int c = tid >> 1, rh = (tid & 1) * 4;
        const h2* __restrict__ w = fwh + (size_t)c * (COMB / 2);
        const float bias = fb[c];
        float acc[4] = {bias, bias, bias, bias};
        for (int t2 = 0; t2 < COMB / 2; t2 += 4) {
            const float4 wraw = *reinterpret_cast<const float4*>(w + t2);
            const h2 w0 = __builtin_bit_cast(h2, wraw.x);
            const h2 w1 = __builtin_bit_cast(h2, wraw.y);
            const h2 w2 = __builtin_bit_cast(h2, wraw.z);
            const h2 w3 = __builtin_bit_cast(h2, wraw.w);
#pragma unroll
            for (int r = 0; r < 4; ++r) {
                const float4 craw = *reinterpret_cast<const float4*>(&sch[rh + r][t2]);
                acc[r] = __builtin_amdgcn_fdot2(__builtin_bit_cast(h2, craw.x), w0, acc[r], false);
                acc[r] = __builtin_amdgcn_fdot2(__builtin_bit_cast(h2, craw.y), w1, acc[r], false);
                acc[r] = __builtin_amdgcn_fdot2(__builtin_bit_cast(h2, craw.z), w2, acc[r], false);
                acc[r] = __builtin_amdgcn_fdot2(__builtin_bit_cast(h2, craw.w), w3, acc[r], false);
            }
        }
#pragma unroll
        for (int r = 0; r < 4; ++r) {
            out[(size_t)(r0 + rh + r) * OUTD + c] = fmaxf(acc[r], 0.f);
        }
    }
}

__global__ __launch_bounds__(512) void mlp_kernel_fb(const float* __restrict__ pooled,
                                                     const float* __restrict__ lw,
                                                     const float* __restrict__ lb,
                                                     const float* __restrict__ fw,
                                                     const float* __restrict__ fb,
                                                     float* __restrict__ out) {
    __shared__ h2 sph[8][COMB / 2];
    __shared__ h2 sch[8][COMB / 2];
    const int tid = threadIdx.x;
    const int r0 = blockIdx.x * 8;
    const float2* __restrict__ srcp = reinterpret_cast<const float2*>(pooled + (size_t)r0 * COMB);
    for (int i = tid; i < 8 * (COMB / 2); i += 512) {
        const float2 v = srcp[i];
        (&sph[0][0])[i] = __builtin_amdgcn_cvt_pkrtz(v.x, v.y);
    }
    __syncthreads();
    for (int c = tid; c < COMB; c += 512) {
        const float* __restrict__ w = lw + (size_t)c * POOLP;
        const int lb2 = (c >> 7) * (POOLP / 2);
        const float bias = lb[c];
        float acc[8];
#pragma unroll
        for (int r = 0; r < 8; ++r) acc[r] = bias;
        for (int t2 = 0; t2 < POOLP / 2; t2 += 4) {
            const float4 wa = *reinterpret_cast<const float4*>(w + t2 * 2);
            const float4 wb = *reinterpret_cast<const float4*>(w + t2 * 2 + 4);
            const h2 w0 = __builtin_amdgcn_cvt_pkrtz(wa.x, wa.y);
            const h2 w1 = __builtin_amdgcn_cvt_pkrtz(wa.z, wa.w);
            const h2 w2 = __builtin_amdgcn_cvt_pkrtz(wb.x, wb.y);
            const h2 w3 = __builtin_amdgcn_cvt_pkrtz(wb.z, wb.w);
#pragma unroll
            for (int r = 0; r < 8; ++r) {
                const float4 raw = *reinterpret_cast<const float4*>(&sph[r][lb2 + t2]);
                acc[r] = __builtin_amdgcn_fdot2(__builtin_bit_cast(h2, raw.x), w0, acc[r], false);
                acc[r] = __builtin_amdgcn_fdot2(__builtin_bit_cast(h2, raw.y), w1, acc[r], false);
                acc[r] = __builtin_amdgcn_fdot2(__builtin_bit_cast(h2, raw.z), w2, acc[r], false);
                acc[r] = __builtin_amdgcn_fdot2(__builtin_bit_cast(h2, raw.w), w3, acc[r], false);
            }
        }
        __fp16* __restrict__ schf = reinterpret_cast<__fp16*>(&sch[0][0]);
#pragma unroll
        for (int r = 0; r < 8; ++r) schf[r * COMB + c] = (__fp16)fmaxf(acc[r], 0.f);
    }
    __syncthreads();
    {
        const int j = tid;
        const float* __restrict__ w = fw + (size_t)j * COMB;
        const float bias = fb[j];
        float acc[8];
#pragma unroll
        for (int r = 0; r < 8; ++r) acc[r] = bias;
        for (int t2 = 0; t2 < COMB / 2; t2 += 4) {
            const float4 wa = *reinterpret_cast<const float4*>(w + t2 * 2);
            const float4 wb = *reinterpret_cast<const float4*>(w + t2 * 2 + 4);
            const h2 w0 = __builtin_amdgcn_cvt_pkrtz(wa.x, wa.y);
            const h2 w1 = __builtin_amdgcn_cvt_pkrtz(wa.z, wa.w);
            const h2 w2 = __builtin_amdgcn_cvt_pkrtz(wb.x, wb.y);
            const h2 w3 = __builtin_amdgcn_cvt_pkrtz(wb.z, wb.w);
#pragma unroll
            for (int r = 0; r < 8; ++r) {
                const float4 raw = *reinterpret_cast<const float4*>(&sch[r][t2]);
                acc[r] = __builtin_amdgcn_fdot2(__builtin_bit_cast(h2, raw.x), w0, acc[r], false);
                acc[r] = __builtin_amdgcn_fdot2(__builtin_bit_cast(h2, raw.y), w1, acc[r], false);
                acc[r] = __builtin_amdgcn_fdot2(__builtin_bit_cast(h2, raw.z), w2, acc[r], false);
                acc[r] = __builtin_amdgcn_fdot2(__builtin_bit_cast(h2, raw.w), w3, acc[r], false);
            }
        }
#pragma unroll
        for (int r = 0; r < 8; ++r) {
            out[(size_t)(r0 + r) * OUTD + j] = fmaxf(acc[r], 0.f);
        }
    }
}

extern "C" void kernel_launch(void* const* d_in, const int* in_sizes, int n_in,
                              void* d_out, int out_size, void* d_ws, size_t ws_size,
                              hipStream_t stream) {
    const float* x  = (const float*)d_in[0];
    const float* lw = (const float*)d_in[1];
    const float* lb = (const float*)d_in[2];
    const float* fw = (const float*)d_in[3];
    const float* fb = (const float*)d_in[4];
    float* out = (float*)d_out;

    char* base = (char*)d_ws;
    const size_t POOLED_B = (size_t)BATCH * COMB * 4;            // 5,242,880
    const size_t LWH_B    = (size_t)LW_PAIRS * 4;                // 163,840
    const size_t FWH_B    = (size_t)FW_PAIRS * 4;                // 655,360
    const size_t META_B   = (size_t)COMB * 4;                    // 2,560 (pad to 16B ok)
    const size_t WT_B     = (size_t)COMB * WLEN * 2;             // 573,440

    float* pooled = (float*)base;
    h2*  lwh  = (h2*)(base + POOLED_B);
    h2*  fwh  = (h2*)(base + POOLED_B + LWH_B);
    int* meta = (int*)(base + POOLED_B + LWH_B + FWH_B);
    h2*  wt   = (h2*)(base + POOLED_B + LWH_B + FWH_B + ((META_B + 15) & ~15ull));

    const size_t NEED_MLP    = POOLED_B + LWH_B + FWH_B;
    const size_t NEED_BANDED = NEED_MLP + ((META_B + 15) & ~15ull) + WT_B;

    if (ws_size >= NEED_BANDED) {
        build_w<<<COMB, 128, 0, stream>>>(wt, meta);
        banded_kernel<<<BATCH, 512, 0, stream>>>(x, wt, meta, pooled);
    } else {
        dwt_pool_kernel<<<BATCH * 2, NTHR, 0, stream>>>(x, pooled);
    }

    if (ws_size >= NEED_MLP) {
        pack_w<<<(LW_PAIRS + FW_PAIRS + 255) / 256, 256, 0, stream>>>(lw, fw, lwh, fwh);
        mlp_kernel<<<BATCH / 8, 1024, 0, stream>>>(pooled, lwh, lb, fwh, fb, out);
    } else {
        mlp_kernel_fb<<<BATCH / 8, 512, 0, stream>>>(pooled, lw, lb, fw, fb, out);
    }
}